// Round 12
// baseline (134.102 us; speedup 1.0000x reference)
//
#include <hip/hip_runtime.h>

// LocalSelfAttention2d fused MFMA, R12 = R6 anchor + two critical-path edits:
//  (a) pass-A ks=0/1 weight fragments prefetched BEFORE staging (L2 latency
//      hides under staging's HBM wait; k-loop starts MFMA immediately post-B0).
//  (b) y-transpose scratch moved from xs-overlay to the wave's private slice
//      (dead after PV) -> barrier B3 deleted (4 -> 3 barriers).
// Everything else identical to R6/R11 (126.5us anchor).

typedef __attribute__((ext_vector_type(8))) short bf16x8;
typedef __attribute__((ext_vector_type(4))) float f32x4;

#define NWROW 17
#define NWIN  289
#define ATT_SCALE 0.17677669529663687f  // 1/sqrt(32)

// LDS geometry (ushort units)
#define XS_STRIDE 264                    // 528B rows (16B aligned)
#define XS_SIZE   (64 * XS_STRIDE)       // 16896 ush = 33792 B (os overlays this)
#define WPRIV     2560                   // per-wave private scratch (5120 B)
#define LDS_USH   (XS_SIZE + 8 * WPRIV)  // 37376 ush = 74752 B -> 2 blocks/CU

__device__ __forceinline__ ushort f2bf(float f) {
    unsigned u = __float_as_uint(f);
    u += 0x7FFFu + ((u >> 16) & 1u);   // RNE
    return (ushort)(u >> 16);
}
__device__ __forceinline__ unsigned pack2(float a, float b) {
    return (unsigned)f2bf(a) | ((unsigned)f2bf(b) << 16);
}

__global__ void lsa_wconv(const float* __restrict__ wqkv,
                          const float* __restrict__ wout,
                          ushort* __restrict__ dst)
{
    int n = blockIdx.x * 256 + threadIdx.x;   // 1024 x 256 = 262144
    float v = (n < 196608) ? wqkv[n] : wout[n - 196608];
    dst[n] = f2bf(v);
}

__global__ __launch_bounds__(512, 4)
void lsa_fused(const float* __restrict__ x,
               const float* __restrict__ bqkv,
               const float* __restrict__ posb,
               const float* __restrict__ bout,
               const ushort* __restrict__ wqkvb,
               const ushort* __restrict__ woutb,
               float* __restrict__ y)
{
    __shared__ __align__(16) ushort sm[LDS_USH];

    const int t    = threadIdx.x;
    const int wv   = t >> 6;        // wave = head
    const int lane = t & 63;
    const int g    = lane >> 4;     // 0..3
    const int c    = lane & 15;     // 0..15
    const int head = wv;

    // bijective XCD chunk swizzle (nwg=1156: q=144, r=4)
    const int orig = blockIdx.x;
    const int xcd  = orig & 7;
    const int idx  = orig >> 3;
    const int bid  = (xcd < 4 ? xcd * 145 : 580 + (xcd - 4) * 144) + idx;

    const int b   = bid / NWIN;
    const int win = bid - b * NWIN;
    const int wi  = win / NWROW;
    const int wj  = win - wi * NWROW;
    const int hbase = wi * 8 - 4;
    const int wbase = wj * 8 - 4;

    // ---- pass-A weight pointers + ks=0/1 prefetch (independent of staging) ----
    const ushort* wr[4];
    #pragma unroll
    for (int j = 0; j < 4; ++j) {
        int m0 = (j >> 1) * 256 + head * 32 + (j & 1) * 16;   // sect 0=q,1=k
        wr[j] = wqkvb + (size_t)(m0 + c) * 256;
    }
    bf16x8 af0[4], af1[4];
    #pragma unroll
    for (int j = 0; j < 4; ++j) {
        af0[j] = *(const bf16x8*)(wr[j] + 8 * g);
        af1[j] = *(const bf16x8*)(wr[j] + 32 + 8 * g);
    }

    // ---------------- phase 0: stage x tile (bf16 [pos][ch]) ----------------
    #pragma unroll
    for (int i = 0; i < 8; ++i) {
        int id = (i << 9) + t;
        int ch = id >> 4;
        int qd = id & 15;           // hh = qd>>1, wquad = qd&1
        int h  = hbase + (qd >> 1);
        int w0 = wbase + (qd & 1) * 4;
        f32x4 v = (f32x4){0.f, 0.f, 0.f, 0.f};
        if ((unsigned)h < 128u && (unsigned)w0 < 125u)
            v = *(const f32x4*)&x[(((size_t)b * 256 + ch) * 128 + h) * 128 + w0];
        ushort bs[4] = {f2bf(v[0]), f2bf(v[1]), f2bf(v[2]), f2bf(v[3])};
        #pragma unroll
        for (int e = 0; e < 4; ++e) {
            int ee = (e + qd) & 3;
            sm[(qd * 4 + ee) * XS_STRIDE + ch] = bs[ee];
        }
    }
    __syncthreads();   // B0 (drains prefetch too -> af0/af1 ready in regs)

    ushort* priv = &sm[XS_SIZE + wv * WPRIV];

    // ---------------- pass A: q,k projection (4 m-tiles x 4 p-tiles) ----------------
    f32x4 acc[4][4];
    #pragma unroll
    for (int i = 0; i < 4; ++i)
        #pragma unroll
        for (int j = 0; j < 4; ++j)
            acc[i][j] = (f32x4){0.f, 0.f, 0.f, 0.f};

    // ks = 0, 1 with prefetched A-frags
    {
        bf16x8 bfr[4];
        #pragma unroll
        for (int pt = 0; pt < 4; ++pt)
            bfr[pt] = *(const bf16x8*)&sm[(pt * 16 + c) * XS_STRIDE + 8 * g];
        #pragma unroll
        for (int j = 0; j < 4; ++j)
            #pragma unroll
            for (int pt = 0; pt < 4; ++pt)
                acc[j][pt] = __builtin_amdgcn_mfma_f32_16x16x32_bf16(af0[j], bfr[pt], acc[j][pt], 0, 0, 0);
        #pragma unroll
        for (int pt = 0; pt < 4; ++pt)
            bfr[pt] = *(const bf16x8*)&sm[(pt * 16 + c) * XS_STRIDE + 32 + 8 * g];
        #pragma unroll
        for (int j = 0; j < 4; ++j)
            #pragma unroll
            for (int pt = 0; pt < 4; ++pt)
                acc[j][pt] = __builtin_amdgcn_mfma_f32_16x16x32_bf16(af1[j], bfr[pt], acc[j][pt], 0, 0, 0);
    }
    #pragma unroll
    for (int ks = 2; ks < 8; ++ks) {
        bf16x8 bfr[4];
        #pragma unroll
        for (int pt = 0; pt < 4; ++pt)
            bfr[pt] = *(const bf16x8*)&sm[(pt * 16 + c) * XS_STRIDE + ks * 32 + 8 * g];
        #pragma unroll
        for (int j = 0; j < 4; ++j) {
            bf16x8 afr = *(const bf16x8*)(wr[j] + ks * 32 + 8 * g);
            #pragma unroll
            for (int pt = 0; pt < 4; ++pt)
                acc[j][pt] = __builtin_amdgcn_mfma_f32_16x16x32_bf16(afr, bfr[pt], acc[j][pt], 0, 0, 0);
        }
    }

    // q epilogue -> Qt[pos][32d] stride 40 (injective: row len 32 <= 40)
    #pragma unroll
    for (int mt = 0; mt < 2; ++mt) {
        f32x4 bq = *(const f32x4*)&bqkv[head * 32 + mt * 16 + 4 * g];
        #pragma unroll
        for (int pt = 0; pt < 4; ++pt) {
            const int pos = pt * 16 + c;
            const float* pb = posb + (size_t)(head * 32 + mt * 16 + 4 * g) * 64 + pos;
            float v0 = (acc[mt][pt][0] + bq[0] + pb[0])   * ATT_SCALE;
            float v1 = (acc[mt][pt][1] + bq[1] + pb[64])  * ATT_SCALE;
            float v2 = (acc[mt][pt][2] + bq[2] + pb[128]) * ATT_SCALE;
            float v3 = (acc[mt][pt][3] + bq[3] + pb[192]) * ATT_SCALE;
            *(unsigned*)&priv[pos * 40 + mt * 16 + 4 * g]     = pack2(v0, v1);
            *(unsigned*)&priv[pos * 40 + mt * 16 + 4 * g + 2] = pack2(v2, v3);
        }
    }
    bf16x8 qf[4];
    #pragma unroll
    for (int qt = 0; qt < 4; ++qt)
        qf[qt] = *(const bf16x8*)&priv[(qt * 16 + c) * 40 + 8 * g];

    // k epilogue -> Kt (same slots; same-wave RAW through in-order DS pipe)
    #pragma unroll
    for (int mt = 0; mt < 2; ++mt) {
        f32x4 bk = *(const f32x4*)&bqkv[256 + head * 32 + mt * 16 + 4 * g];
        #pragma unroll
        for (int pt = 0; pt < 4; ++pt) {
            const int pos = pt * 16 + c;
            *(unsigned*)&priv[pos * 40 + mt * 16 + 4 * g]     = pack2(acc[mt + 2][pt][0] + bk[0], acc[mt + 2][pt][1] + bk[1]);
            *(unsigned*)&priv[pos * 40 + mt * 16 + 4 * g + 2] = pack2(acc[mt + 2][pt][2] + bk[2], acc[mt + 2][pt][3] + bk[3]);
        }
    }
    bf16x8 kf[4];
    #pragma unroll
    for (int kt = 0; kt < 4; ++kt)
        kf[kt] = *(const bf16x8*)&priv[(kt * 16 + c) * 40 + 8 * g];

    // ---------------- pass B: v projection (2 m-tiles x 4 p-tiles) ----------------
    f32x4 av[2][4];
    #pragma unroll
    for (int i = 0; i < 2; ++i)
        #pragma unroll
        for (int j = 0; j < 4; ++j)
            av[i][j] = (f32x4){0.f, 0.f, 0.f, 0.f};
    const ushort* wv0 = wqkvb + (size_t)(512 + head * 32 + c) * 256;
    const ushort* wv1 = wqkvb + (size_t)(512 + head * 32 + 16 + c) * 256;

    #pragma unroll
    for (int ks = 0; ks < 8; ++ks) {
        bf16x8 bfr[4];
        #pragma unroll
        for (int pt = 0; pt < 4; ++pt)
            bfr[pt] = *(const bf16x8*)&sm[(pt * 16 + c) * XS_STRIDE + ks * 32 + 8 * g];
        bf16x8 a0 = *(const bf16x8*)(wv0 + ks * 32 + 8 * g);
        bf16x8 a1 = *(const bf16x8*)(wv1 + ks * 32 + 8 * g);
        #pragma unroll
        for (int pt = 0; pt < 4; ++pt) {
            av[0][pt] = __builtin_amdgcn_mfma_f32_16x16x32_bf16(a0, bfr[pt], av[0][pt], 0, 0, 0);
            av[1][pt] = __builtin_amdgcn_mfma_f32_16x16x32_bf16(a1, bfr[pt], av[1][pt], 0, 0, 0);
        }
    }

    // v epilogue -> VT[32 d][64 pos] STRIDE 72 (injective; overwrites Qt/Kt)
    #pragma unroll
    for (int mt = 0; mt < 2; ++mt) {
        f32x4 bv = *(const f32x4*)&bqkv[512 + head * 32 + mt * 16 + 4 * g];
        #pragma unroll
        for (int pt = 0; pt < 4; ++pt) {
            #pragma unroll
            for (int r = 0; r < 4; ++r)
                priv[(mt * 16 + 4 * g + r) * 72 + pt * 16 + c] = f2bf(av[mt][pt][r] + bv[r]);
        }
    }

    // ---------------- attention (fully wave-private, no barriers) ----------------
    f32x4 s[4][4];   // [kt][qt]: D row = key kt*16+4g+r, col = query qt*16+c
    #pragma unroll
    for (int kt = 0; kt < 4; ++kt)
        #pragma unroll
        for (int qt = 0; qt < 4; ++qt)
            s[kt][qt] = __builtin_amdgcn_mfma_f32_16x16x32_bf16(kf[kt], qf[qt],
                                                                (f32x4){0.f,0.f,0.f,0.f}, 0, 0, 0);

    float rinv[4];
    #pragma unroll
    for (int qt = 0; qt < 4; ++qt) {
        float mx = s[0][qt][0];
        #pragma unroll
        for (int kt = 0; kt < 4; ++kt)
            #pragma unroll
            for (int r = 0; r < 4; ++r)
                mx = fmaxf(mx, s[kt][qt][r]);
        mx = fmaxf(mx, __shfl_xor(mx, 16));
        mx = fmaxf(mx, __shfl_xor(mx, 32));
        float sum = 0.f;
        #pragma unroll
        for (int kt = 0; kt < 4; ++kt)
            #pragma unroll
            for (int r = 0; r < 4; ++r) {
                s[kt][qt][r] = __expf(s[kt][qt][r] - mx);
                sum += s[kt][qt][r];
            }
        sum += __shfl_xor(sum, 16);
        sum += __shfl_xor(sum, 32);
        rinv[qt] = 1.0f / sum;
    }

    // vf BEFORE P overwrites VT
    bf16x8 vf[2][2];
    #pragma unroll
    for (int dt = 0; dt < 2; ++dt)
        #pragma unroll
        for (int k2 = 0; k2 < 2; ++k2)
            vf[dt][k2] = *(const bf16x8*)&priv[(dt * 16 + c) * 72 + k2 * 32 + 8 * g];

    // PV in two sequential key-half generations through the same P slots
    f32x4 o[2][4];
    #pragma unroll
    for (int dt = 0; dt < 2; ++dt)
        #pragma unroll
        for (int qt = 0; qt < 4; ++qt)
            o[dt][qt] = (f32x4){0.f,0.f,0.f,0.f};

    #pragma unroll
    for (int k2 = 0; k2 < 2; ++k2) {
        #pragma unroll
        for (int qt = 0; qt < 4; ++qt)
            #pragma unroll
            for (int kl = 0; kl < 2; ++kl) {
                const int kt = k2 * 2 + kl;
                *(unsigned*)&priv[(qt * 16 + c) * 40 + kl * 16 + 4 * g]     = pack2(s[kt][qt][0], s[kt][qt][1]);
                *(unsigned*)&priv[(qt * 16 + c) * 40 + kl * 16 + 4 * g + 2] = pack2(s[kt][qt][2], s[kt][qt][3]);
            }
        #pragma unroll
        for (int qt = 0; qt < 4; ++qt) {
            bf16x8 pf = *(const bf16x8*)&priv[(qt * 16 + c) * 40 + 8 * g];
            #pragma unroll
            for (int dt = 0; dt < 2; ++dt)
                o[dt][qt] = __builtin_amdgcn_mfma_f32_16x16x32_bf16(vf[dt][k2], pf, o[dt][qt], 0, 0, 0);
        }
    }

    __syncthreads();   // B1: every wave done reading xs; o may overlay it

    // o -> os[pos][ch] (xs overlay)
    #pragma unroll
    for (int dt = 0; dt < 2; ++dt)
        #pragma unroll
        for (int qt = 0; qt < 4; ++qt) {
            const int pos = qt * 16 + c;
            const int ch0 = head * 32 + dt * 16 + 4 * g;
            float rv = rinv[qt];
            *(unsigned*)&sm[pos * XS_STRIDE + ch0]     = pack2(o[dt][qt][0]*rv, o[dt][qt][1]*rv);
            *(unsigned*)&sm[pos * XS_STRIDE + ch0 + 2] = pack2(o[dt][qt][2]*rv, o[dt][qt][3]*rv);
        }
    __syncthreads();   // B2: os complete

    // ---------------- out projection: wave owns out-ch wv*32..+31, K=256 ----------------
    f32x4 ya[2][4];
    #pragma unroll
    for (int i = 0; i < 2; ++i)
        #pragma unroll
        for (int j = 0; j < 4; ++j)
            ya[i][j] = (f32x4){0.f,0.f,0.f,0.f};

    const ushort* wo0 = woutb + (size_t)(wv * 32 + c) * 256;
    const ushort* wo1 = woutb + (size_t)(wv * 32 + 16 + c) * 256;

    #pragma unroll
    for (int ks = 0; ks < 8; ++ks) {
        bf16x8 ofr[4];
        #pragma unroll
        for (int pt = 0; pt < 4; ++pt)
            ofr[pt] = *(const bf16x8*)&sm[(pt * 16 + c) * XS_STRIDE + ks * 32 + 8 * g];
        bf16x8 a0 = *(const bf16x8*)(wo0 + ks * 32 + 8 * g);
        bf16x8 a1 = *(const bf16x8*)(wo1 + ks * 32 + 8 * g);
        #pragma unroll
        for (int pt = 0; pt < 4; ++pt) {
            ya[0][pt] = __builtin_amdgcn_mfma_f32_16x16x32_bf16(a0, ofr[pt], ya[0][pt], 0, 0, 0);
            ya[1][pt] = __builtin_amdgcn_mfma_f32_16x16x32_bf16(a1, ofr[pt], ya[1][pt], 0, 0, 0);
        }
    }
    // NO B3: y-transpose scratch is the wave's private slice (priv dead after PV)

    // ---------------- epilogue: per-wave transpose in priv -> float4 y stores ----------------
    float* ysp = (float*)priv;        // [16 rows][66] f32 = 4224B <= 5120B, wave-private
    #pragma unroll
    for (int mt = 0; mt < 2; ++mt) {
        f32x4 bo = *(const f32x4*)&bout[wv * 32 + mt * 16 + 4 * g];
        #pragma unroll
        for (int pt = 0; pt < 4; ++pt) {
            const int pos = pt * 16 + c;
            #pragma unroll
            for (int r = 0; r < 4; ++r)
                ysp[(4 * g + r) * 66 + pos] = ya[mt][pt][r] + bo[r];
        }
        #pragma unroll
        for (int k = 0; k < 2; ++k) {
            const int cl = k * 8 + (lane >> 3);   // 0..15 local out-channel
            const int hh = lane & 7;
            float2 p0 = *(float2*)&ysp[cl * 66 + hh * 8];
            float2 p1 = *(float2*)&ysp[cl * 66 + hh * 8 + 2];
            float2 p2 = *(float2*)&ysp[cl * 66 + hh * 8 + 4];
            float2 p3 = *(float2*)&ysp[cl * 66 + hh * 8 + 6];
            const int co  = wv * 32 + mt * 16 + cl;
            const int him = wi * 8 + hh - 4;
            if ((unsigned)him < 128u) {
                float* yrow = y + (((size_t)b * 256 + co) * 128 + him) * 128;
                if (wj > 0)  { f32x4 v0 = {p0.x, p0.y, p1.x, p1.y}; *(f32x4*)&yrow[wbase]     = v0; }
                if (wj < 16) { f32x4 v1 = {p2.x, p2.y, p3.x, p3.y}; *(f32x4*)&yrow[wbase + 4] = v1; }
            }
        }
    }
}

extern "C" void kernel_launch(void* const* d_in, const int* in_sizes, int n_in,
                              void* d_out, int out_size, void* d_ws, size_t ws_size,
                              hipStream_t stream)
{
    const float* x    = (const float*)d_in[0];
    const float* wqkv = (const float*)d_in[1];
    const float* bqkv = (const float*)d_in[2];
    const float* posb = (const float*)d_in[3];
    const float* wout = (const float*)d_in[4];
    const float* bout = (const float*)d_in[5];
    float* y = (float*)d_out;

    ushort* wqkvb = (ushort*)d_ws;            // 196608 bf16
    ushort* woutb = wqkvb + 196608;           // 65536 bf16

    lsa_wconv<<<dim3(1024), dim3(256), 0, stream>>>(wqkv, wout, wqkvb);
    lsa_fused<<<dim3(4 * NWIN), dim3(512), 0, stream>>>(x, bqkv, posb, bout, wqkvb, woutb, y);
}

// Round 13
// 125.876 us; speedup vs baseline: 1.0654x; 1.0654x over previous
//
#include <hip/hip_runtime.h>

// LocalSelfAttention2d fused MFMA, R13 = R6 anchor + B3-deletion ONLY.
// (R12 bundled this with a weight prefetch that spilled; this isolates the
//  unconvicted edit.) y-transpose scratch moved from xs-overlay to the wave's
// private slice (dead after PV) -> 3 barriers total. No new live registers.
// B=4, CIN=HC=256, heads=8, dh=32, P=8, img 128x128, pad 4/4, 17x17 win.

typedef __attribute__((ext_vector_type(8))) short bf16x8;
typedef __attribute__((ext_vector_type(4))) float f32x4;

#define NWROW 17
#define NWIN  289
#define ATT_SCALE 0.17677669529663687f  // 1/sqrt(32)

// LDS geometry (ushort units)
#define XS_STRIDE 264                    // 528B rows (16B aligned)
#define XS_SIZE   (64 * XS_STRIDE)       // 16896 ush = 33792 B (os overlays this)
#define WPRIV     2560                   // per-wave private scratch (5120 B)
#define LDS_USH   (XS_SIZE + 8 * WPRIV)  // 37376 ush = 74752 B -> 2 blocks/CU

__device__ __forceinline__ ushort f2bf(float f) {
    unsigned u = __float_as_uint(f);
    u += 0x7FFFu + ((u >> 16) & 1u);   // RNE
    return (ushort)(u >> 16);
}
__device__ __forceinline__ unsigned pack2(float a, float b) {
    return (unsigned)f2bf(a) | ((unsigned)f2bf(b) << 16);
}

__global__ void lsa_wconv(const float* __restrict__ wqkv,
                          const float* __restrict__ wout,
                          ushort* __restrict__ dst)
{
    int n = blockIdx.x * 256 + threadIdx.x;   // 1024 x 256 = 262144
    float v = (n < 196608) ? wqkv[n] : wout[n - 196608];
    dst[n] = f2bf(v);
}

__global__ __launch_bounds__(512, 4)
void lsa_fused(const float* __restrict__ x,
               const float* __restrict__ bqkv,
               const float* __restrict__ posb,
               const float* __restrict__ bout,
               const ushort* __restrict__ wqkvb,
               const ushort* __restrict__ woutb,
               float* __restrict__ y)
{
    __shared__ __align__(16) ushort sm[LDS_USH];

    const int t    = threadIdx.x;
    const int wv   = t >> 6;        // wave = head
    const int lane = t & 63;
    const int g    = lane >> 4;     // 0..3
    const int c    = lane & 15;     // 0..15
    const int head = wv;

    // bijective XCD chunk swizzle (nwg=1156: q=144, r=4)
    const int orig = blockIdx.x;
    const int xcd  = orig & 7;
    const int idx  = orig >> 3;
    const int bid  = (xcd < 4 ? xcd * 145 : 580 + (xcd - 4) * 144) + idx;

    const int b   = bid / NWIN;
    const int win = bid - b * NWIN;
    const int wi  = win / NWROW;
    const int wj  = win - wi * NWROW;
    const int hbase = wi * 8 - 4;
    const int wbase = wj * 8 - 4;

    // ---------------- phase 0: stage x tile (bf16 [pos][ch]) ----------------
    #pragma unroll
    for (int i = 0; i < 8; ++i) {
        int id = (i << 9) + t;
        int ch = id >> 4;
        int qd = id & 15;           // hh = qd>>1, wquad = qd&1
        int h  = hbase + (qd >> 1);
        int w0 = wbase + (qd & 1) * 4;
        f32x4 v = (f32x4){0.f, 0.f, 0.f, 0.f};
        if ((unsigned)h < 128u && (unsigned)w0 < 125u)
            v = *(const f32x4*)&x[(((size_t)b * 256 + ch) * 128 + h) * 128 + w0];
        ushort bs[4] = {f2bf(v[0]), f2bf(v[1]), f2bf(v[2]), f2bf(v[3])};
        #pragma unroll
        for (int e = 0; e < 4; ++e) {
            int ee = (e + qd) & 3;
            sm[(qd * 4 + ee) * XS_STRIDE + ch] = bs[ee];
        }
    }
    __syncthreads();   // B0

    ushort* priv = &sm[XS_SIZE + wv * WPRIV];

    // ---------------- pass A: q,k projection (4 m-tiles x 4 p-tiles) ----------------
    f32x4 acc[4][4];
    #pragma unroll
    for (int i = 0; i < 4; ++i)
        #pragma unroll
        for (int j = 0; j < 4; ++j)
            acc[i][j] = (f32x4){0.f, 0.f, 0.f, 0.f};

    const ushort* wr[4];
    #pragma unroll
    for (int j = 0; j < 4; ++j) {
        int m0 = (j >> 1) * 256 + head * 32 + (j & 1) * 16;   // sect 0=q,1=k
        wr[j] = wqkvb + (size_t)(m0 + c) * 256;
    }

    #pragma unroll
    for (int ks = 0; ks < 8; ++ks) {
        bf16x8 bfr[4];
        #pragma unroll
        for (int pt = 0; pt < 4; ++pt)
            bfr[pt] = *(const bf16x8*)&sm[(pt * 16 + c) * XS_STRIDE + ks * 32 + 8 * g];
        #pragma unroll
        for (int j = 0; j < 4; ++j) {
            bf16x8 afr = *(const bf16x8*)(wr[j] + ks * 32 + 8 * g);
            #pragma unroll
            for (int pt = 0; pt < 4; ++pt)
                acc[j][pt] = __builtin_amdgcn_mfma_f32_16x16x32_bf16(afr, bfr[pt], acc[j][pt], 0, 0, 0);
        }
    }

    // q epilogue -> Qt[pos][32d] stride 40 (injective: row len 32 <= 40)
    #pragma unroll
    for (int mt = 0; mt < 2; ++mt) {
        f32x4 bq = *(const f32x4*)&bqkv[head * 32 + mt * 16 + 4 * g];
        #pragma unroll
        for (int pt = 0; pt < 4; ++pt) {
            const int pos = pt * 16 + c;
            const float* pb = posb + (size_t)(head * 32 + mt * 16 + 4 * g) * 64 + pos;
            float v0 = (acc[mt][pt][0] + bq[0] + pb[0])   * ATT_SCALE;
            float v1 = (acc[mt][pt][1] + bq[1] + pb[64])  * ATT_SCALE;
            float v2 = (acc[mt][pt][2] + bq[2] + pb[128]) * ATT_SCALE;
            float v3 = (acc[mt][pt][3] + bq[3] + pb[192]) * ATT_SCALE;
            *(unsigned*)&priv[pos * 40 + mt * 16 + 4 * g]     = pack2(v0, v1);
            *(unsigned*)&priv[pos * 40 + mt * 16 + 4 * g + 2] = pack2(v2, v3);
        }
    }
    bf16x8 qf[4];
    #pragma unroll
    for (int qt = 0; qt < 4; ++qt)
        qf[qt] = *(const bf16x8*)&priv[(qt * 16 + c) * 40 + 8 * g];

    // k epilogue -> Kt (same slots; same-wave RAW through in-order DS pipe)
    #pragma unroll
    for (int mt = 0; mt < 2; ++mt) {
        f32x4 bk = *(const f32x4*)&bqkv[256 + head * 32 + mt * 16 + 4 * g];
        #pragma unroll
        for (int pt = 0; pt < 4; ++pt) {
            const int pos = pt * 16 + c;
            *(unsigned*)&priv[pos * 40 + mt * 16 + 4 * g]     = pack2(acc[mt + 2][pt][0] + bk[0], acc[mt + 2][pt][1] + bk[1]);
            *(unsigned*)&priv[pos * 40 + mt * 16 + 4 * g + 2] = pack2(acc[mt + 2][pt][2] + bk[2], acc[mt + 2][pt][3] + bk[3]);
        }
    }
    bf16x8 kf[4];
    #pragma unroll
    for (int kt = 0; kt < 4; ++kt)
        kf[kt] = *(const bf16x8*)&priv[(kt * 16 + c) * 40 + 8 * g];

    // ---------------- pass B: v projection (2 m-tiles x 4 p-tiles) ----------------
    f32x4 av[2][4];
    #pragma unroll
    for (int i = 0; i < 2; ++i)
        #pragma unroll
        for (int j = 0; j < 4; ++j)
            av[i][j] = (f32x4){0.f, 0.f, 0.f, 0.f};
    const ushort* wv0 = wqkvb + (size_t)(512 + head * 32 + c) * 256;
    const ushort* wv1 = wqkvb + (size_t)(512 + head * 32 + 16 + c) * 256;

    #pragma unroll
    for (int ks = 0; ks < 8; ++ks) {
        bf16x8 bfr[4];
        #pragma unroll
        for (int pt = 0; pt < 4; ++pt)
            bfr[pt] = *(const bf16x8*)&sm[(pt * 16 + c) * XS_STRIDE + ks * 32 + 8 * g];
        bf16x8 a0 = *(const bf16x8*)(wv0 + ks * 32 + 8 * g);
        bf16x8 a1 = *(const bf16x8*)(wv1 + ks * 32 + 8 * g);
        #pragma unroll
        for (int pt = 0; pt < 4; ++pt) {
            av[0][pt] = __builtin_amdgcn_mfma_f32_16x16x32_bf16(a0, bfr[pt], av[0][pt], 0, 0, 0);
            av[1][pt] = __builtin_amdgcn_mfma_f32_16x16x32_bf16(a1, bfr[pt], av[1][pt], 0, 0, 0);
        }
    }

    // v epilogue -> VT[32 d][64 pos] STRIDE 72 (injective; overwrites Qt/Kt)
    #pragma unroll
    for (int mt = 0; mt < 2; ++mt) {
        f32x4 bv = *(const f32x4*)&bqkv[512 + head * 32 + mt * 16 + 4 * g];
        #pragma unroll
        for (int pt = 0; pt < 4; ++pt) {
            #pragma unroll
            for (int r = 0; r < 4; ++r)
                priv[(mt * 16 + 4 * g + r) * 72 + pt * 16 + c] = f2bf(av[mt][pt][r] + bv[r]);
        }
    }

    // ---------------- attention (fully wave-private, no barriers) ----------------
    f32x4 s[4][4];   // [kt][qt]: D row = key kt*16+4g+r, col = query qt*16+c
    #pragma unroll
    for (int kt = 0; kt < 4; ++kt)
        #pragma unroll
        for (int qt = 0; qt < 4; ++qt)
            s[kt][qt] = __builtin_amdgcn_mfma_f32_16x16x32_bf16(kf[kt], qf[qt],
                                                                (f32x4){0.f,0.f,0.f,0.f}, 0, 0, 0);

    float rinv[4];
    #pragma unroll
    for (int qt = 0; qt < 4; ++qt) {
        float mx = s[0][qt][0];
        #pragma unroll
        for (int kt = 0; kt < 4; ++kt)
            #pragma unroll
            for (int r = 0; r < 4; ++r)
                mx = fmaxf(mx, s[kt][qt][r]);
        mx = fmaxf(mx, __shfl_xor(mx, 16));
        mx = fmaxf(mx, __shfl_xor(mx, 32));
        float sum = 0.f;
        #pragma unroll
        for (int kt = 0; kt < 4; ++kt)
            #pragma unroll
            for (int r = 0; r < 4; ++r) {
                s[kt][qt][r] = __expf(s[kt][qt][r] - mx);
                sum += s[kt][qt][r];
            }
        sum += __shfl_xor(sum, 16);
        sum += __shfl_xor(sum, 32);
        rinv[qt] = 1.0f / sum;
    }

    // vf BEFORE P overwrites VT
    bf16x8 vf[2][2];
    #pragma unroll
    for (int dt = 0; dt < 2; ++dt)
        #pragma unroll
        for (int k2 = 0; k2 < 2; ++k2)
            vf[dt][k2] = *(const bf16x8*)&priv[(dt * 16 + c) * 72 + k2 * 32 + 8 * g];

    // PV in two sequential key-half generations through the same P slots
    f32x4 o[2][4];
    #pragma unroll
    for (int dt = 0; dt < 2; ++dt)
        #pragma unroll
        for (int qt = 0; qt < 4; ++qt)
            o[dt][qt] = (f32x4){0.f,0.f,0.f,0.f};

    #pragma unroll
    for (int k2 = 0; k2 < 2; ++k2) {
        #pragma unroll
        for (int qt = 0; qt < 4; ++qt)
            #pragma unroll
            for (int kl = 0; kl < 2; ++kl) {
                const int kt = k2 * 2 + kl;
                *(unsigned*)&priv[(qt * 16 + c) * 40 + kl * 16 + 4 * g]     = pack2(s[kt][qt][0], s[kt][qt][1]);
                *(unsigned*)&priv[(qt * 16 + c) * 40 + kl * 16 + 4 * g + 2] = pack2(s[kt][qt][2], s[kt][qt][3]);
            }
        #pragma unroll
        for (int qt = 0; qt < 4; ++qt) {
            bf16x8 pf = *(const bf16x8*)&priv[(qt * 16 + c) * 40 + 8 * g];
            #pragma unroll
            for (int dt = 0; dt < 2; ++dt)
                o[dt][qt] = __builtin_amdgcn_mfma_f32_16x16x32_bf16(vf[dt][k2], pf, o[dt][qt], 0, 0, 0);
        }
    }

    __syncthreads();   // B1: every wave done reading xs; o may overlay it

    // o -> os[pos][ch] (xs overlay)
    #pragma unroll
    for (int dt = 0; dt < 2; ++dt)
        #pragma unroll
        for (int qt = 0; qt < 4; ++qt) {
            const int pos = qt * 16 + c;
            const int ch0 = head * 32 + dt * 16 + 4 * g;
            float rv = rinv[qt];
            *(unsigned*)&sm[pos * XS_STRIDE + ch0]     = pack2(o[dt][qt][0]*rv, o[dt][qt][1]*rv);
            *(unsigned*)&sm[pos * XS_STRIDE + ch0 + 2] = pack2(o[dt][qt][2]*rv, o[dt][qt][3]*rv);
        }
    __syncthreads();   // B2: os complete

    // ---------------- out projection: wave owns out-ch wv*32..+31, K=256 ----------------
    f32x4 ya[2][4];
    #pragma unroll
    for (int i = 0; i < 2; ++i)
        #pragma unroll
        for (int j = 0; j < 4; ++j)
            ya[i][j] = (f32x4){0.f,0.f,0.f,0.f};

    const ushort* wo0 = woutb + (size_t)(wv * 32 + c) * 256;
    const ushort* wo1 = woutb + (size_t)(wv * 32 + 16 + c) * 256;

    #pragma unroll
    for (int ks = 0; ks < 8; ++ks) {
        bf16x8 ofr[4];
        #pragma unroll
        for (int pt = 0; pt < 4; ++pt)
            ofr[pt] = *(const bf16x8*)&sm[(pt * 16 + c) * XS_STRIDE + ks * 32 + 8 * g];
        bf16x8 a0 = *(const bf16x8*)(wo0 + ks * 32 + 8 * g);
        bf16x8 a1 = *(const bf16x8*)(wo1 + ks * 32 + 8 * g);
        #pragma unroll
        for (int pt = 0; pt < 4; ++pt) {
            ya[0][pt] = __builtin_amdgcn_mfma_f32_16x16x32_bf16(a0, ofr[pt], ya[0][pt], 0, 0, 0);
            ya[1][pt] = __builtin_amdgcn_mfma_f32_16x16x32_bf16(a1, ofr[pt], ya[1][pt], 0, 0, 0);
        }
    }
    // NO B3: y-transpose scratch is the wave's private slice (priv dead after PV)

    // ---------------- epilogue: per-wave transpose in priv -> float4 y stores ----------------
    float* ysp = (float*)priv;        // [16 rows][66] f32 = 4224B <= 5120B, wave-private
    #pragma unroll
    for (int mt = 0; mt < 2; ++mt) {
        f32x4 bo = *(const f32x4*)&bout[wv * 32 + mt * 16 + 4 * g];
        #pragma unroll
        for (int pt = 0; pt < 4; ++pt) {
            const int pos = pt * 16 + c;
            #pragma unroll
            for (int r = 0; r < 4; ++r)
                ysp[(4 * g + r) * 66 + pos] = ya[mt][pt][r] + bo[r];
        }
        #pragma unroll
        for (int k = 0; k < 2; ++k) {
            const int cl = k * 8 + (lane >> 3);   // 0..15 local out-channel
            const int hh = lane & 7;
            float2 p0 = *(float2*)&ysp[cl * 66 + hh * 8];
            float2 p1 = *(float2*)&ysp[cl * 66 + hh * 8 + 2];
            float2 p2 = *(float2*)&ysp[cl * 66 + hh * 8 + 4];
            float2 p3 = *(float2*)&ysp[cl * 66 + hh * 8 + 6];
            const int co  = wv * 32 + mt * 16 + cl;
            const int him = wi * 8 + hh - 4;
            if ((unsigned)him < 128u) {
                float* yrow = y + (((size_t)b * 256 + co) * 128 + him) * 128;
                if (wj > 0)  { f32x4 v0 = {p0.x, p0.y, p1.x, p1.y}; *(f32x4*)&yrow[wbase]     = v0; }
                if (wj < 16) { f32x4 v1 = {p2.x, p2.y, p3.x, p3.y}; *(f32x4*)&yrow[wbase + 4] = v1; }
            }
        }
    }
}

extern "C" void kernel_launch(void* const* d_in, const int* in_sizes, int n_in,
                              void* d_out, int out_size, void* d_ws, size_t ws_size,
                              hipStream_t stream)
{
    const float* x    = (const float*)d_in[0];
    const float* wqkv = (const float*)d_in[1];
    const float* bqkv = (const float*)d_in[2];
    const float* posb = (const float*)d_in[3];
    const float* wout = (const float*)d_in[4];
    const float* bout = (const float*)d_in[5];
    float* y = (float*)d_out;

    ushort* wqkvb = (ushort*)d_ws;            // 196608 bf16
    ushort* woutb = wqkvb + 196608;           // 65536 bf16

    lsa_wconv<<<dim3(1024), dim3(256), 0, stream>>>(wqkv, wout, wqkvb);
    lsa_fused<<<dim3(4 * NWIN), dim3(512), 0, stream>>>(x, bqkv, posb, bout, wqkvb, woutb, y);
}